// Round 4
// baseline (311.408 us; speedup 1.0000x reference)
//
#include <hip/hip_runtime.h>

#define H_ 448
#define W_ 96
#define CIN_ 128
#define HW_ (H_*W_)   // 43008

__device__ __forceinline__ float lrelu(float v){ return v > 0.0f ? v : 0.01f*v; }

// Counting sort of 96 pixels by class (NC classes). All threads must call.
template<int NC>
__device__ __forceinline__ void sort_by_class(const unsigned char* s_cls, short* s_perm,
                                              int* s_cnt, int* s_off, int t)
{
    if (t < NC){
        int c = 0;
        for (int p = 0; p < 96; p++) if (s_cls[p] == (unsigned char)t) c++;
        s_cnt[t] = c;
    }
    __syncthreads();
    if (t == 0){
        int a = 0;
        for (int c = 0; c < NC; c++){ s_off[c] = a; a += s_cnt[c]; }
    }
    __syncthreads();
    if (t < NC){
        int o = s_off[t];
        for (int p = 0; p < 96; p++) if (s_cls[p] == (unsigned char)t) s_perm[o++] = (short)p;
    }
    __syncthreads();
}

__global__ __launch_bounds__(384, 3)
void cls3_fused(const float* __restrict__ X,
                const float* __restrict__ w1_0, const float* __restrict__ b1_0,
                const float* __restrict__ w1_1, const float* __restrict__ b1_1,
                const float* __restrict__ w1_2, const float* __restrict__ b1_2,
                const float* __restrict__ w2_0, const float* __restrict__ b2_0,
                const float* __restrict__ w2_1, const float* __restrict__ b2_1,
                const float* __restrict__ w2_2, const float* __restrict__ b2_2,
                const float* __restrict__ w3_0, const float* __restrict__ b3_0,
                const float* __restrict__ w3_1, const float* __restrict__ b3_1,
                const float* __restrict__ w3_2, const float* __restrict__ b3_2,
                int* __restrict__ out)
{
    // X line [i=128][w=96] = 48KB; stage-1 weights alias the front (dead after stage 1)
    __shared__ float s_X[12288];
    __shared__ float s_A[3456];      // activations ping (stage1: stride 33; stage2/3: stride 36)
    __shared__ float s_B[3456];      // activations pong
    __shared__ unsigned char s_cls[96];
    __shared__ short s_perm[96];
    __shared__ int   s_raw[96];
    __shared__ int   s_cnt[64];
    __shared__ int   s_off[64];

    float* s_w0 = s_X;               // 4096  [o=32][i=128]
    float* s_w1 = s_X + 4096;        // 1024  [o=32][i=32]
    float* s_w2 = s_X + 5120;        // 256   [o=8][i=32]

    const int h  = blockIdx.x;
    const int t  = threadIdx.x;

    // ================= stage 1 (w=pixel, s owns 8 channels) =================
    {
        const int w  = t % 96;
        const int s  = t / 96;
        const int hw = h*96 + w;

        const float* g0 = w1_0 + (size_t)h*4096;
        for (int j = t; j < 4096; j += 384) s_w0[j] = g0[j];
        const float* g1 = w1_1 + (size_t)h*1024;
        for (int j = t; j < 1024; j += 384) s_w1[j] = g1[j];
        const float* g2 = w1_2 + (size_t)h*256;
        for (int j = t; j < 256; j += 384) s_w2[j] = g2[j];
        __syncthreads();

        // L0: 128 -> 32 (X from global, coalesced)
        {
            float acc[8];
            const float* bp = b1_0 + h*32 + s*8;
            #pragma unroll
            for (int k=0;k<8;k++) acc[k] = bp[k];
            #pragma unroll 4
            for (int i4=0;i4<32;i4++){
                const float x0 = X[(size_t)(4*i4+0)*HW_ + hw];
                const float x1 = X[(size_t)(4*i4+1)*HW_ + hw];
                const float x2 = X[(size_t)(4*i4+2)*HW_ + hw];
                const float x3 = X[(size_t)(4*i4+3)*HW_ + hw];
                #pragma unroll
                for (int k=0;k<8;k++){
                    const float4 q = *(const float4*)&s_w0[(s*8+k)*128 + 4*i4];
                    acc[k] += x0*q.x; acc[k] += x1*q.y; acc[k] += x2*q.z; acc[k] += x3*q.w;
                }
            }
            #pragma unroll
            for (int k=0;k<8;k++) s_A[w*33 + s*8 + k] = lrelu(acc[k]);
        }
        __syncthreads();

        // L1: 32 -> 32
        {
            float acc[8];
            const float* bp = b1_1 + h*32 + s*8;
            #pragma unroll
            for (int k=0;k<8;k++) acc[k] = bp[k];
            #pragma unroll
            for (int i4=0;i4<8;i4++){
                const float x0 = s_A[w*33 + 4*i4+0];
                const float x1 = s_A[w*33 + 4*i4+1];
                const float x2 = s_A[w*33 + 4*i4+2];
                const float x3 = s_A[w*33 + 4*i4+3];
                #pragma unroll
                for (int k=0;k<8;k++){
                    const float4 q = *(const float4*)&s_w1[(s*8+k)*32 + 4*i4];
                    acc[k] += x0*q.x; acc[k] += x1*q.y; acc[k] += x2*q.z; acc[k] += x3*q.w;
                }
            }
            #pragma unroll
            for (int k=0;k<8;k++) s_B[w*33 + s*8 + k] = lrelu(acc[k]);
        }
        __syncthreads();

        // L2: 32 -> 8 (each s owns 2 outputs)
        {
            float acc[2];
            const float* bp = b1_2 + h*8 + s*2;
            acc[0] = bp[0]; acc[1] = bp[1];
            #pragma unroll
            for (int i4=0;i4<8;i4++){
                const float x0 = s_B[w*33 + 4*i4+0];
                const float x1 = s_B[w*33 + 4*i4+1];
                const float x2 = s_B[w*33 + 4*i4+2];
                const float x3 = s_B[w*33 + 4*i4+3];
                #pragma unroll
                for (int k=0;k<2;k++){
                    const float4 q = *(const float4*)&s_w2[(s*2+k)*32 + 4*i4];
                    acc[k] += x0*q.x; acc[k] += x1*q.y; acc[k] += x2*q.z; acc[k] += x3*q.w;
                }
            }
            s_A[w*33 + s*2 + 0] = acc[0];
            s_A[w*33 + s*2 + 1] = acc[1];
        }
        __syncthreads();

        if (s == 0){
            const float* sc = &s_A[w*33];
            float best = sc[0]; int bi = 0;
            #pragma unroll
            for (int k=1;k<8;k++){ const float v = sc[k]; if (v > best){ best = v; bi = k; } }
            s_cls[w] = (unsigned char)bi;
        }
        __syncthreads();   // stage-1 weights now dead; s_cls published
    }

    // ---- stage the X line into LDS (overwrites stage-1 weight region) ----
    {
        const float* xg = X + h*96;
        for (int j = t; j < 12288; j += 384){
            const int i = j / 96;
            const int w = j - i*96;
            s_X[j] = xg[(size_t)i*HW_ + w];
        }
    }
    __syncthreads();

    // sort pixels by stage-1 class (8 classes)
    sort_by_class<8>(s_cls, s_perm, s_cnt, s_off, t);

    // ================= stage 2 (p=sorted pixel, q owns 8 channels) =================
    const int p = t >> 2;
    const int q = t & 3;
    {
        const int sp = s_perm[p];
        const int c  = s_cls[sp];
        const long e = (long)h*8 + c;
        const float* W0 = w2_0 + e*4096 + q*8;
        const float* W1 = w2_1 + e*1024 + q*8;
        const float* W2 = w2_2 + e*512  + q*4;

        // L0: 128 -> 32 (pure weight stream; X broadcast from LDS)
        float acc[8];
        {
            const float4 bv0 = *(const float4*)&b2_0[e*32 + q*8];
            const float4 bv1 = *(const float4*)&b2_0[e*32 + q*8 + 4];
            acc[0]=bv0.x; acc[1]=bv0.y; acc[2]=bv0.z; acc[3]=bv0.w;
            acc[4]=bv1.x; acc[5]=bv1.y; acc[6]=bv1.z; acc[7]=bv1.w;
        }
        #pragma unroll 16
        for (int i=0;i<128;i++){
            const float xv = s_X[i*96 + sp];
            const float4 a = *(const float4*)&W0[i*32];
            const float4 b = *(const float4*)&W0[i*32 + 4];
            acc[0]+=xv*a.x; acc[1]+=xv*a.y; acc[2]+=xv*a.z; acc[3]+=xv*a.w;
            acc[4]+=xv*b.x; acc[5]+=xv*b.y; acc[6]+=xv*b.z; acc[7]+=xv*b.w;
        }
        *(float4*)&s_A[p*36 + q*8]     = make_float4(lrelu(acc[0]),lrelu(acc[1]),lrelu(acc[2]),lrelu(acc[3]));
        *(float4*)&s_A[p*36 + q*8 + 4] = make_float4(lrelu(acc[4]),lrelu(acc[5]),lrelu(acc[6]),lrelu(acc[7]));
        __syncthreads();

        // L1: 32 -> 32
        float ac2[8];
        {
            const float4 bv0 = *(const float4*)&b2_1[e*32 + q*8];
            const float4 bv1 = *(const float4*)&b2_1[e*32 + q*8 + 4];
            ac2[0]=bv0.x; ac2[1]=bv0.y; ac2[2]=bv0.z; ac2[3]=bv0.w;
            ac2[4]=bv1.x; ac2[5]=bv1.y; ac2[6]=bv1.z; ac2[7]=bv1.w;
        }
        #pragma unroll 8
        for (int i=0;i<32;i++){
            const float xv = s_A[p*36 + i];
            const float4 a = *(const float4*)&W1[i*32];
            const float4 b = *(const float4*)&W1[i*32 + 4];
            ac2[0]+=xv*a.x; ac2[1]+=xv*a.y; ac2[2]+=xv*a.z; ac2[3]+=xv*a.w;
            ac2[4]+=xv*b.x; ac2[5]+=xv*b.y; ac2[6]+=xv*b.z; ac2[7]+=xv*b.w;
        }
        *(float4*)&s_B[p*36 + q*8]     = make_float4(lrelu(ac2[0]),lrelu(ac2[1]),lrelu(ac2[2]),lrelu(ac2[3]));
        *(float4*)&s_B[p*36 + q*8 + 4] = make_float4(lrelu(ac2[4]),lrelu(ac2[5]),lrelu(ac2[6]),lrelu(ac2[7]));
        __syncthreads();

        // L2: 32 -> 16 (each lane owns 4 channels)
        float4 sc = *(const float4*)&b2_2[e*16 + q*4];
        #pragma unroll 8
        for (int i=0;i<32;i++){
            const float xv = s_B[p*36 + i];
            const float4 r = *(const float4*)&W2[i*16];
            sc.x += xv*r.x; sc.y += xv*r.y; sc.z += xv*r.z; sc.w += xv*r.w;
        }
        float best = sc.x; int bi = q*4;
        if (sc.y > best){ best = sc.y; bi = q*4+1; }
        if (sc.z > best){ best = sc.z; bi = q*4+2; }
        if (sc.w > best){ best = sc.w; bi = q*4+3; }
        #pragma unroll
        for (int off=1; off<4; off<<=1){
            const float ob = __shfl_xor(best, off, 64);
            const int  obi = __shfl_xor(bi,  off, 64);
            if (ob > best || (ob == best && obi < bi)){ best = ob; bi = obi; }
        }
        __syncthreads();
        if (q == 0){
            const int raw = c*8 + bi - 4;
            s_raw[sp] = raw;
            s_cls[sp] = (unsigned char)(raw < 0 ? 0 : (raw > 63 ? 63 : raw));
        }
        __syncthreads();
    }

    // sort pixels by clipped inds12 (64 classes)
    sort_by_class<64>(s_cls, s_perm, s_cnt, s_off, t);

    // ================= stage 3 =================
    {
        const int sp = s_perm[p];
        const int c  = s_cls[sp];
        const long e = (long)h*64 + c;
        const float* W0 = w3_0 + e*4096 + q*8;
        const float* W1 = w3_1 + e*1024 + q*8;
        const float* W2 = w3_2 + e*512  + q*4;

        float acc[8];
        {
            const float4 bv0 = *(const float4*)&b3_0[e*32 + q*8];
            const float4 bv1 = *(const float4*)&b3_0[e*32 + q*8 + 4];
            acc[0]=bv0.x; acc[1]=bv0.y; acc[2]=bv0.z; acc[3]=bv0.w;
            acc[4]=bv1.x; acc[5]=bv1.y; acc[6]=bv1.z; acc[7]=bv1.w;
        }
        #pragma unroll 16
        for (int i=0;i<128;i++){
            const float xv = s_X[i*96 + sp];
            const float4 a = *(const float4*)&W0[i*32];
            const float4 b = *(const float4*)&W0[i*32 + 4];
            acc[0]+=xv*a.x; acc[1]+=xv*a.y; acc[2]+=xv*a.z; acc[3]+=xv*a.w;
            acc[4]+=xv*b.x; acc[5]+=xv*b.y; acc[6]+=xv*b.z; acc[7]+=xv*b.w;
        }
        *(float4*)&s_A[p*36 + q*8]     = make_float4(lrelu(acc[0]),lrelu(acc[1]),lrelu(acc[2]),lrelu(acc[3]));
        *(float4*)&s_A[p*36 + q*8 + 4] = make_float4(lrelu(acc[4]),lrelu(acc[5]),lrelu(acc[6]),lrelu(acc[7]));
        __syncthreads();

        float ac2[8];
        {
            const float4 bv0 = *(const float4*)&b3_1[e*32 + q*8];
            const float4 bv1 = *(const float4*)&b3_1[e*32 + q*8 + 4];
            ac2[0]=bv0.x; ac2[1]=bv0.y; ac2[2]=bv0.z; ac2[3]=bv0.w;
            ac2[4]=bv1.x; ac2[5]=bv1.y; ac2[6]=bv1.z; ac2[7]=bv1.w;
        }
        #pragma unroll 8
        for (int i=0;i<32;i++){
            const float xv = s_A[p*36 + i];
            const float4 a = *(const float4*)&W1[i*32];
            const float4 b = *(const float4*)&W1[i*32 + 4];
            ac2[0]+=xv*a.x; ac2[1]+=xv*a.y; ac2[2]+=xv*a.z; ac2[3]+=xv*a.w;
            ac2[4]+=xv*b.x; ac2[5]+=xv*b.y; ac2[6]+=xv*b.z; ac2[7]+=xv*b.w;
        }
        *(float4*)&s_B[p*36 + q*8]     = make_float4(lrelu(ac2[0]),lrelu(ac2[1]),lrelu(ac2[2]),lrelu(ac2[3]));
        *(float4*)&s_B[p*36 + q*8 + 4] = make_float4(lrelu(ac2[4]),lrelu(ac2[5]),lrelu(ac2[6]),lrelu(ac2[7]));
        __syncthreads();

        float4 sc = *(const float4*)&b3_2[e*16 + q*4];
        #pragma unroll 8
        for (int i=0;i<32;i++){
            const float xv = s_B[p*36 + i];
            const float4 r = *(const float4*)&W2[i*16];
            sc.x += xv*r.x; sc.y += xv*r.y; sc.z += xv*r.z; sc.w += xv*r.w;
        }
        float best = sc.x; int bi = q*4;
        if (sc.y > best){ best = sc.y; bi = q*4+1; }
        if (sc.z > best){ best = sc.z; bi = q*4+2; }
        if (sc.w > best){ best = sc.w; bi = q*4+3; }
        #pragma unroll
        for (int off=1; off<4; off<<=1){
            const float ob = __shfl_xor(best, off, 64);
            const int  obi = __shfl_xor(bi,  off, 64);
            if (ob > best || (ob == best && obi < bi)){ best = ob; bi = obi; }
        }
        if (q == 0){
            int v = s_raw[sp]*8 + bi - 4;
            v = v < 0 ? 0 : (v > 511 ? 511 : v);
            out[h*96 + sp] = v;
        }
    }
}

extern "C" void kernel_launch(void* const* d_in, const int* in_sizes, int n_in,
                              void* d_out, int out_size, void* d_ws, size_t ws_size,
                              hipStream_t stream) {
    const float* X    = (const float*)d_in[0];
    const float* w1_0 = (const float*)d_in[1];
    const float* b1_0 = (const float*)d_in[2];
    const float* w1_1 = (const float*)d_in[3];
    const float* b1_1 = (const float*)d_in[4];
    const float* w1_2 = (const float*)d_in[5];
    const float* b1_2 = (const float*)d_in[6];
    const float* w2_0 = (const float*)d_in[7];
    const float* b2_0 = (const float*)d_in[8];
    const float* w2_1 = (const float*)d_in[9];
    const float* b2_1 = (const float*)d_in[10];
    const float* w2_2 = (const float*)d_in[11];
    const float* b2_2 = (const float*)d_in[12];
    const float* w3_0 = (const float*)d_in[13];
    const float* b3_0 = (const float*)d_in[14];
    const float* w3_1 = (const float*)d_in[15];
    const float* b3_1 = (const float*)d_in[16];
    const float* w3_2 = (const float*)d_in[17];
    const float* b3_2 = (const float*)d_in[18];
    int* out = (int*)d_out;

    cls3_fused<<<H_, 384, 0, stream>>>(X,
        w1_0, b1_0, w1_1, b1_1, w1_2, b1_2,
        w2_0, b2_0, w2_1, b2_1, w2_2, b2_2,
        w3_0, b3_0, w3_1, b3_1, w3_2, b3_2,
        out);
}

// Round 5
// 152.516 us; speedup vs baseline: 2.0418x; 2.0418x over previous
//
#include <hip/hip_runtime.h>

#define H_ 448
#define W_ 96
#define CIN_ 128
#define HW_ (H_*W_)   // 43008
#define PPB 48        // pixels per block (half line)

__device__ __forceinline__ float lrelu(float v){ return v > 0.0f ? v : 0.01f*v; }

// Counting sort of PPB pixels by class (NC classes). All threads must call.
template<int NC>
__device__ __forceinline__ void sort_by_class(const unsigned char* s_cls, short* s_perm,
                                              int* s_cnt, int* s_off, int t)
{
    if (t < NC){
        int c = 0;
        for (int p = 0; p < PPB; p++) if (s_cls[p] == (unsigned char)t) c++;
        s_cnt[t] = c;
    }
    __syncthreads();
    if (t == 0){
        int a = 0;
        for (int c = 0; c < NC; c++){ s_off[c] = a; a += s_cnt[c]; }
    }
    __syncthreads();
    if (t < NC){
        int o = s_off[t];
        for (int p = 0; p < PPB; p++) if (s_cls[p] == (unsigned char)t) s_perm[o++] = (short)p;
    }
    __syncthreads();
}

__global__ __launch_bounds__(384, 6)
void cls3_fused(const float* __restrict__ X,
                const float* __restrict__ w1_0, const float* __restrict__ b1_0,
                const float* __restrict__ w1_1, const float* __restrict__ b1_1,
                const float* __restrict__ w1_2, const float* __restrict__ b1_2,
                const float* __restrict__ w2_0, const float* __restrict__ b2_0,
                const float* __restrict__ w2_1, const float* __restrict__ b2_1,
                const float* __restrict__ w2_2, const float* __restrict__ b2_2,
                const float* __restrict__ w3_0, const float* __restrict__ b3_0,
                const float* __restrict__ w3_1, const float* __restrict__ b3_1,
                const float* __restrict__ w3_2, const float* __restrict__ b3_2,
                int* __restrict__ out)
{
    __shared__ float s_w0[4096];     // stage-1 w1_0[h]  [o=32][i=128]
    __shared__ float s_w1[1024];     // stage-1 w1_1[h]  [o=32][i=32]
    __shared__ float s_w2[256];      // stage-1 w1_2[h]  [o=8][i=32]
    __shared__ float s_A[PPB*36];    // activations ping (stage1: stride 33; stage2/3: stride 36)
    __shared__ float s_B[PPB*36];    // activations pong
    __shared__ unsigned char s_cls[PPB];
    __shared__ short s_perm[PPB];
    __shared__ int   s_raw[PPB];
    __shared__ int   s_cnt[64];
    __shared__ int   s_off[64];

    const int h  = blockIdx.x >> 1;
    const int wb = (blockIdx.x & 1) * PPB;   // pixel-base within the line
    const int t  = threadIdx.x;

    // ================= stage 1 (w=pixel 0..47, s=0..7 owns 4 channels) =================
    {
        const int w  = t % PPB;
        const int s  = t / PPB;
        const int hw = h*96 + wb + w;

        const float* g0 = w1_0 + (size_t)h*4096;
        for (int j = t; j < 4096; j += 384) s_w0[j] = g0[j];
        const float* g1 = w1_1 + (size_t)h*1024;
        for (int j = t; j < 1024; j += 384) s_w1[j] = g1[j];
        const float* g2 = w1_2 + (size_t)h*256;
        for (int j = t; j < 256; j += 384) s_w2[j] = g2[j];
        __syncthreads();

        // L0: 128 -> 32 (X from global, coalesced)
        {
            float acc[4];
            const float* bp = b1_0 + h*32 + s*4;
            #pragma unroll
            for (int k=0;k<4;k++) acc[k] = bp[k];
            #pragma unroll 4
            for (int i4=0;i4<32;i4++){
                const float x0 = X[(size_t)(4*i4+0)*HW_ + hw];
                const float x1 = X[(size_t)(4*i4+1)*HW_ + hw];
                const float x2 = X[(size_t)(4*i4+2)*HW_ + hw];
                const float x3 = X[(size_t)(4*i4+3)*HW_ + hw];
                #pragma unroll
                for (int k=0;k<4;k++){
                    const float4 q = *(const float4*)&s_w0[(s*4+k)*128 + 4*i4];
                    acc[k] += x0*q.x; acc[k] += x1*q.y; acc[k] += x2*q.z; acc[k] += x3*q.w;
                }
            }
            #pragma unroll
            for (int k=0;k<4;k++) s_A[w*33 + s*4 + k] = lrelu(acc[k]);
        }
        __syncthreads();

        // L1: 32 -> 32
        {
            float acc[4];
            const float* bp = b1_1 + h*32 + s*4;
            #pragma unroll
            for (int k=0;k<4;k++) acc[k] = bp[k];
            #pragma unroll
            for (int i4=0;i4<8;i4++){
                const float x0 = s_A[w*33 + 4*i4+0];
                const float x1 = s_A[w*33 + 4*i4+1];
                const float x2 = s_A[w*33 + 4*i4+2];
                const float x3 = s_A[w*33 + 4*i4+3];
                #pragma unroll
                for (int k=0;k<4;k++){
                    const float4 q = *(const float4*)&s_w1[(s*4+k)*32 + 4*i4];
                    acc[k] += x0*q.x; acc[k] += x1*q.y; acc[k] += x2*q.z; acc[k] += x3*q.w;
                }
            }
            #pragma unroll
            for (int k=0;k<4;k++) s_B[w*33 + s*4 + k] = lrelu(acc[k]);
        }
        __syncthreads();

        // L2: 32 -> 8 (each s owns 1 output)
        {
            float acc = b1_2[h*8 + s];
            #pragma unroll
            for (int i4=0;i4<8;i4++){
                const float4 q = *(const float4*)&s_w2[s*32 + 4*i4];
                acc += s_B[w*33 + 4*i4+0]*q.x;
                acc += s_B[w*33 + 4*i4+1]*q.y;
                acc += s_B[w*33 + 4*i4+2]*q.z;
                acc += s_B[w*33 + 4*i4+3]*q.w;
            }
            s_A[w*33 + s] = acc;
        }
        __syncthreads();

        if (s == 0){
            const float* sc = &s_A[w*33];
            float best = sc[0]; int bi = 0;
            #pragma unroll
            for (int k=1;k<8;k++){ const float v = sc[k]; if (v > best){ best = v; bi = k; } }
            s_cls[w] = (unsigned char)bi;
        }
        __syncthreads();
    }

    // sort pixels by stage-1 class (8 classes)
    sort_by_class<8>(s_cls, s_perm, s_cnt, s_off, t);

    // ================= stage 2 (p=sorted pixel 0..47, j=0..7 owns 4 channels) =================
    const int p = t >> 3;
    const int j = t & 7;
    {
        const int sp = s_perm[p];
        const int c  = s_cls[sp];
        const long e = (long)h*8 + c;
        const int hw = h*96 + wb + sp;
        const float* W0 = w2_0 + e*4096 + j*4;
        const float* W1 = w2_1 + e*1024 + j*4;
        const float* W2 = w2_2 + e*512  + j*2;

        // L0: 128 -> 32 (8 lanes/pixel cover one 128B expert row)
        float4 acc = *(const float4*)&b2_0[e*32 + j*4];
        #pragma unroll 8
        for (int i=0;i<128;i++){
            const float xv = X[(size_t)i*HW_ + hw];
            const float4 q = *(const float4*)&W0[i*32];
            acc.x += xv*q.x; acc.y += xv*q.y; acc.z += xv*q.z; acc.w += xv*q.w;
        }
        *(float4*)&s_A[p*36 + j*4] = make_float4(lrelu(acc.x),lrelu(acc.y),lrelu(acc.z),lrelu(acc.w));
        __syncthreads();

        // L1: 32 -> 32
        float4 ac2 = *(const float4*)&b2_1[e*32 + j*4];
        #pragma unroll 8
        for (int i=0;i<32;i++){
            const float xv = s_A[p*36 + i];
            const float4 q = *(const float4*)&W1[i*32];
            ac2.x += xv*q.x; ac2.y += xv*q.y; ac2.z += xv*q.z; ac2.w += xv*q.w;
        }
        *(float4*)&s_B[p*36 + j*4] = make_float4(lrelu(ac2.x),lrelu(ac2.y),lrelu(ac2.z),lrelu(ac2.w));
        __syncthreads();

        // L2: 32 -> 16 (each lane owns 2 channels)
        float2 sc = *(const float2*)&b2_2[e*16 + j*2];
        #pragma unroll 8
        for (int i=0;i<32;i++){
            const float xv = s_B[p*36 + i];
            const float2 r = *(const float2*)&W2[i*16];
            sc.x += xv*r.x; sc.y += xv*r.y;
        }
        float best = sc.x; int bi = j*2;
        if (sc.y > best){ best = sc.y; bi = j*2+1; }
        #pragma unroll
        for (int off=1; off<8; off<<=1){
            const float ob = __shfl_xor(best, off, 64);
            const int  obi = __shfl_xor(bi,  off, 64);
            if (ob > best || (ob == best && obi < bi)){ best = ob; bi = obi; }
        }
        __syncthreads();
        if (j == 0){
            const int raw = c*8 + bi - 4;
            s_raw[sp] = raw;
            s_cls[sp] = (unsigned char)(raw < 0 ? 0 : (raw > 63 ? 63 : raw));
        }
        __syncthreads();
    }

    // sort pixels by clipped inds12 (64 classes)
    sort_by_class<64>(s_cls, s_perm, s_cnt, s_off, t);

    // ================= stage 3 =================
    {
        const int sp = s_perm[p];
        const int c  = s_cls[sp];
        const long e = (long)h*64 + c;
        const int hw = h*96 + wb + sp;
        const float* W0 = w3_0 + e*4096 + j*4;
        const float* W1 = w3_1 + e*1024 + j*4;
        const float* W2 = w3_2 + e*512  + j*2;

        float4 acc = *(const float4*)&b3_0[e*32 + j*4];
        #pragma unroll 8
        for (int i=0;i<128;i++){
            const float xv = X[(size_t)i*HW_ + hw];
            const float4 q = *(const float4*)&W0[i*32];
            acc.x += xv*q.x; acc.y += xv*q.y; acc.z += xv*q.z; acc.w += xv*q.w;
        }
        *(float4*)&s_A[p*36 + j*4] = make_float4(lrelu(acc.x),lrelu(acc.y),lrelu(acc.z),lrelu(acc.w));
        __syncthreads();

        float4 ac2 = *(const float4*)&b3_1[e*32 + j*4];
        #pragma unroll 8
        for (int i=0;i<32;i++){
            const float xv = s_A[p*36 + i];
            const float4 q = *(const float4*)&W1[i*32];
            ac2.x += xv*q.x; ac2.y += xv*q.y; ac2.z += xv*q.z; ac2.w += xv*q.w;
        }
        *(float4*)&s_B[p*36 + j*4] = make_float4(lrelu(ac2.x),lrelu(ac2.y),lrelu(ac2.z),lrelu(ac2.w));
        __syncthreads();

        float2 sc = *(const float2*)&b3_2[e*16 + j*2];
        #pragma unroll 8
        for (int i=0;i<32;i++){
            const float xv = s_B[p*36 + i];
            const float2 r = *(const float2*)&W2[i*16];
            sc.x += xv*r.x; sc.y += xv*r.y;
        }
        float best = sc.x; int bi = j*2;
        if (sc.y > best){ best = sc.y; bi = j*2+1; }
        #pragma unroll
        for (int off=1; off<8; off<<=1){
            const float ob = __shfl_xor(best, off, 64);
            const int  obi = __shfl_xor(bi,  off, 64);
            if (ob > best || (ob == best && obi < bi)){ best = ob; bi = obi; }
        }
        if (j == 0){
            int v = s_raw[sp]*8 + bi - 4;
            v = v < 0 ? 0 : (v > 511 ? 511 : v);
            out[h*96 + wb + sp] = v;
        }
    }
}

extern "C" void kernel_launch(void* const* d_in, const int* in_sizes, int n_in,
                              void* d_out, int out_size, void* d_ws, size_t ws_size,
                              hipStream_t stream) {
    const float* X    = (const float*)d_in[0];
    const float* w1_0 = (const float*)d_in[1];
    const float* b1_0 = (const float*)d_in[2];
    const float* w1_1 = (const float*)d_in[3];
    const float* b1_1 = (const float*)d_in[4];
    const float* w1_2 = (const float*)d_in[5];
    const float* b1_2 = (const float*)d_in[6];
    const float* w2_0 = (const float*)d_in[7];
    const float* b2_0 = (const float*)d_in[8];
    const float* w2_1 = (const float*)d_in[9];
    const float* b2_1 = (const float*)d_in[10];
    const float* w2_2 = (const float*)d_in[11];
    const float* b2_2 = (const float*)d_in[12];
    const float* w3_0 = (const float*)d_in[13];
    const float* b3_0 = (const float*)d_in[14];
    const float* w3_1 = (const float*)d_in[15];
    const float* b3_1 = (const float*)d_in[16];
    const float* w3_2 = (const float*)d_in[17];
    const float* b3_2 = (const float*)d_in[18];
    int* out = (int*)d_out;

    cls3_fused<<<H_*2, 384, 0, stream>>>(X,
        w1_0, b1_0, w1_1, b1_1, w1_2, b1_2,
        w2_0, b2_0, w2_1, b2_1, w2_2, b2_2,
        w3_0, b3_0, w3_1, b3_1, w3_2, b3_2,
        out);
}